// Round 9
// baseline (122.302 us; speedup 1.0000x reference)
//
#include <hip/hip_runtime.h>
#include <hip/hip_fp16.h>
#include <math.h>

// CTC loss forward, SINGLE fused kernel v3. One block of 1024 threads
// (16 waves) per batch element; B=256 blocks = 256 CUs.
// LINEAR-domain recurrence (beta transform), math identical to rounds 7/8
// (absmax = 1 bf16 ulp):
//     nO = (aO + pE + skip*pO) * w,  w = e^{x_lab - x_blank} clamped to
//          [6.1e-5, 8192];  nE = aE + aO;  state0 = r0;
//     w = 0 for lanes >= label_length (junk-state flush fix, r6).
// Round-8 lesson: the ZERO-lag renorm put a ~150-cyc serial reduction on the
// chain every 8 steps (chain ~25us of the 42us kernel). v3 uses LAG-4 renorm:
// measure max at window start (row_shr DPP + readlane combine -- the r6-proven
// reduction, NOT r5's broken row_bcast), apply the scale at the NEXT window.
// Overflow-safe by construction: growth/step <= 3*2^13 < 2^14.6, so
// post-apply max <= 2^59.3 and pre-apply max <= 2^117.6 < 2^127. Insurance
// clamp at 1.3e36 (> healthy ceiling 2^117.6 ~ 2.4e35? no: 2^117.6=2.4e35 <
// 1.3e36) is a no-op when healthy. Scales are exact powers of 2 (tracked in
// Rtot) -> semantics-neutral.
// B=256, T=512, C=128 (blank=127), L=64, S=129.

constexpr int Cc = 128;
constexpr int Tt = 512;
constexpr int Ll = 64;
constexpr int NCk = Tt / 8;           // 64 chunks of 8 timesteps
constexpr float INV_LN2 = 1.4426950408889634f;
constexpr float LN2_F   = 0.6931471805599453f;

__device__ __forceinline__ float fexp2(float x) { return __builtin_amdgcn_exp2f(x); }
__device__ __forceinline__ float flog2(float x) { return __builtin_amdgcn_logf(x); }

template<int CTRL, bool BC>
__device__ __forceinline__ float dppf(float old, float x) {
    return __int_as_float(__builtin_amdgcn_update_dpp(
        __float_as_int(old), __float_as_int(x), CTRL, 0xF, 0xF, BC));
}
// lane i <- lane i-1 across whole wave; lane 0 <- fill. (silicon-proven r3-r8)
__device__ __forceinline__ float wshr1(float x, float fill) { return dppf<0x138, false>(fill, x); }

__device__ __forceinline__ float rlf(float v, int lane) {
    return __int_as_float(__builtin_amdgcn_readlane(__float_as_int(v), lane));
}
// Row-local (16-lane) reduce; lanes 15/31/47/63 hold row results. (proven r6-r8)
__device__ __forceinline__ float rowsum(float e) {
    e += dppf<0x111, true>(0.f, e);
    e += dppf<0x112, true>(0.f, e);
    e += dppf<0x114, true>(0.f, e);
    e += dppf<0x118, true>(0.f, e);
    return e;
}
__device__ __forceinline__ float rowmax(float m) {   // m >= 0 (0-fill identity)
    m = fmaxf(m, dppf<0x111, true>(0.f, m));
    m = fmaxf(m, dppf<0x112, true>(0.f, m));
    m = fmaxf(m, dppf<0x114, true>(0.f, m));
    m = fmaxf(m, dppf<0x118, true>(0.f, m));
    return m;
}
__device__ __forceinline__ float allmax(float m) {
    m = rowmax(m);
    return fmaxf(fmaxf(rlf(m, 15), rlf(m, 31)), fmaxf(rlf(m, 47), rlf(m, 63)));
}
__device__ __forceinline__ float bperm_f(int srclane, float v) {
    return __int_as_float(__builtin_amdgcn_ds_bpermute(srclane << 2, __float_as_int(v)));
}
__device__ __forceinline__ float gather4(float4 v, int srclane, int csel) {
    const float gx = bperm_f(srclane, v.x), gy = bperm_f(srclane, v.y);
    const float gz = bperm_f(srclane, v.z), gw = bperm_f(srclane, v.w);
    const float lo = (csel & 1) ? gy : gx;
    const float hi = (csel & 1) ? gw : gz;
    return (csel & 2) ? hi : lo;
}

// One 4-step window: apply lagged scale, launch next measure (off-chain),
// run 4 linear steps. Scales are powers of 2 tracked in Rtot.
template<bool GUARD>
__device__ __forceinline__ void window4(const float* wv, const float* ws,
                                        int t0, int inlen,
                                        float& aO, float& aE, float& r0,
                                        float& Rtot, float& pendSc, float& pendR)
{
    // apply pending scale (measured one window ago)
    aO = fminf(aO * pendSc, 1.3e36f);    // clamp = insurance only (healthy max 2^117.6)
    aE = fminf(aE * pendSc, 1.3e36f);
    r0 *= pendSc;
    Rtot += pendR;
    // measure CURRENT max; result consumed next window (latency overlaps steps)
    const float M = allmax(fmaxf(fmaxf(aO, aE), r0));
    int R = (int)(__float_as_uint(M) >> 23) - 127;
    R = (R < -126) ? -126 : ((R > 126) ? 126 : R);
    pendSc = __uint_as_float((unsigned)(127 - R) << 23);
    pendR = (float)R;
    // 4 steps; aO self-loop is a single fmaf
#pragma unroll
    for (int j = 0; j < 4; ++j) {
        if (!GUARD || (t0 + j < inlen)) {
            const float pE = wshr1(aE, r0);     // beta[2l]; lane0: state0
            const float pO = wshr1(aO, 0.0f);   // beta[2l-1]
            const float nO = fmaf(aO, wv[j], fmaf(pO, ws[j], pE * wv[j]));
            aE += aO;
            aO = nO;
        }
    }
}

__global__ __launch_bounds__(1024, 1) void ctc_fused3_kernel(
    const int* __restrict__ y_true,      // [B, 64]
    const float* __restrict__ y_pred,    // [B, T, C]
    const int* __restrict__ in_len,      // [B]
    const int* __restrict__ lab_len,     // [B]
    float* __restrict__ out)             // [B]
{
    __shared__ __half w_lds[Tt / 8][64][8];   // [chunk][lane][t&7], 64 KB
    __shared__ float  ps[16];                 // per-wave blank partial sums (log2)

    const int b   = blockIdx.x;
    const int tid = threadIdx.x;
    const int w   = tid >> 6;            // wave 0..15
    const int l   = tid & 63;

    int inlen = in_len[b]; if (inlen < 1) inlen = 1; if (inlen > Tt) inlen = Tt;
    int LLv   = lab_len[b]; if (LLv < 1) LLv = 1; if (LLv > Ll) LLv = Ll;

    const int lab = y_true[b * Ll + l] & 127;
    const float* rowbase = y_pred + (size_t)b * Tt * Cc;

    // ---------------- prep: wave w handles rows [w*32, w*32+32) ---------------- (proven r8)
    const int half = l >> 5, li = l & 31;
    const int srcA = lab >> 2;           // lane (in low half) holding class `lab`
    const int csel = lab & 3;
    const int tbase = w * 32;
    const bool live = (l < LLv);         // r6 fix: dead lattice lanes -> w = 0

    float4 vb[4];
#pragma unroll
    for (int j = 0; j < 4; ++j)
        vb[j] = ((const float4*)(rowbase + (size_t)(tbase + 2 * j + half) * Cc))[li];

    float acc = 0.0f;                    // sum of lp2_blank over this wave's rows (< inlen)

    for (int i = 0; i < 16; i += 4) {
#pragma unroll
        for (int j = 0; j < 4; ++j) {
            const float4 v = vb[j];
            const int nx = i + 4 + j;
            if (nx < 16)
                vb[j] = ((const float4*)(rowbase + (size_t)(tbase + 2 * nx + half) * Cc))[li];

            const int rA = tbase + 2 * (i + j);
            const int rB = rA + 1;

            // lse (log2) for both rows: row_shr partial sums + readlane combine
            float e = (fexp2(v.x * INV_LN2) + fexp2(v.y * INV_LN2))
                    + (fexp2(v.z * INV_LN2) + fexp2(v.w * INV_LN2));
            e = rowsum(e);
            const float sA = rlf(e, 15) + rlf(e, 31);
            const float sB = rlf(e, 47) + rlf(e, 63);
            const float lsA = flog2(sA), lsB = flog2(sB);
            const float blA = rlf(v.w, 31);      // blank logit, row A (uniform)
            const float blB = rlf(v.w, 63);      // blank logit, row B

            const float lpbA = fmaf(blA, INV_LN2, -lsA);
            const float lpbB = fmaf(blB, INV_LN2, -lsB);
            acc += ((rA < inlen) ? lpbA : 0.0f) + ((rB < inlen) ? lpbB : 0.0f);

            // per-lane label weights -> LDS chunk layout
            const float xA = gather4(v, srcA, csel);
            const float xB = gather4(v, srcA + 32, csel);
            float wA = fminf(fmaxf(fexp2((xA - blA) * INV_LN2), 6.1e-5f), 8192.0f);
            float wB = fminf(fmaxf(fexp2((xB - blB) * INV_LN2), 6.1e-5f), 8192.0f);
            wA = live ? wA : 0.0f;
            wB = live ? wB : 0.0f;
            const unsigned packed =
                  (unsigned)__half_as_ushort(__float2half(wA))
                | ((unsigned)__half_as_ushort(__float2half(wB)) << 16);
            *(unsigned*)&w_lds[rA >> 3][l][rA & 7] = packed;   // rA even: 4B aligned
        }
    }
    if (l == 0) ps[w] = acc;

    __syncthreads();
    if (w != 0) return;

    // ---------------- chain: wave 0, 512-step linear recurrence ----------------
    const int labp = __shfl_up(lab, 1, 64);
    const float skf = ((l >= 1) && (lab != labp)) ? 1.0f : 0.0f;

    float aO = 0.0f, aE = 0.0f, r0 = 1.0f;
    float Rtot = 0.0f, pendSc = 1.0f, pendR = 0.0f;

    const int nchunks = (inlen + 7) >> 3;       // >= 32 for this data
    uint4 A = *(const uint4*)&w_lds[0][l][0];
    for (int c = 0; c < nchunks; ++c) {
        const int nx = (c + 1 < NCk) ? c + 1 : NCk - 1;
        const uint4 Bv = *(const uint4*)&w_lds[nx][l][0];   // prefetch next chunk

        float wv[8], ws[8];
        {
            const __half2 h0 = *reinterpret_cast<const __half2*>(&A.x);
            const __half2 h1 = *reinterpret_cast<const __half2*>(&A.y);
            const __half2 h2 = *reinterpret_cast<const __half2*>(&A.z);
            const __half2 h3 = *reinterpret_cast<const __half2*>(&A.w);
            wv[0] = __low2float(h0); wv[1] = __high2float(h0);
            wv[2] = __low2float(h1); wv[3] = __high2float(h1);
            wv[4] = __low2float(h2); wv[5] = __high2float(h2);
            wv[6] = __low2float(h3); wv[7] = __high2float(h3);
        }
#pragma unroll
        for (int j = 0; j < 8; ++j) ws[j] = skf * wv[j];    // off-chain precompute

        const int t0 = c * 8;
        if (t0 + 8 <= inlen) {
            window4<false>(wv,     ws,     t0,     inlen, aO, aE, r0, Rtot, pendSc, pendR);
            window4<false>(wv + 4, ws + 4, t0 + 4, inlen, aO, aE, r0, Rtot, pendSc, pendR);
        } else {
            window4<true >(wv,     ws,     t0,     inlen, aO, aE, r0, Rtot, pendSc, pendR);
            window4<true >(wv + 4, ws + 4, t0 + 4, inlen, aO, aE, r0, Rtot, pendSc, pendR);
        }
        A = Bv;
    }
    // (pending scale not yet applied is irrelevant: readout uses current states + Rtot)

    // cum_blank (log2): sum the 16 per-wave partials (uniform)
    float cum_b = 0.0f;
#pragma unroll
    for (int q = 0; q < 16; ++q) cum_b += ps[q];

    // readout: states 2*LL (aE) and 2*LL-1 (aO) live on lane LL-1
    const float aEr = __shfl(aE, LLv - 1, 64);
    const float aOr = __shfl(aO, LLv - 1, 64);
    if (l == 0)
        out[b] = -LN2_F * (flog2(fmaxf(aEr + aOr, 1e-37f)) + Rtot + cum_b);
}

extern "C" void kernel_launch(void* const* d_in, const int* in_sizes, int n_in,
                              void* d_out, int out_size, void* d_ws, size_t ws_size,
                              hipStream_t stream) {
    const int*   y_true  = (const int*)d_in[0];    // [256,64]
    const float* y_pred  = (const float*)d_in[1];  // [256,512,128]
    const int*   in_len  = (const int*)d_in[2];    // [256]
    const int*   lab_len = (const int*)d_in[3];    // [256]
    float*       out     = (float*)d_out;          // [256]
    (void)d_ws; (void)ws_size;

    ctc_fused3_kernel<<<256, 1024, 0, stream>>>(y_true, y_pred, in_len, lab_len, out);
}

// Round 10
// 121.133 us; speedup vs baseline: 1.0096x; 1.0096x over previous
//
#include <hip/hip_runtime.h>
#include <hip/hip_fp16.h>
#include <math.h>

// CTC loss forward, SINGLE fused kernel v4. One block of 1024 threads
// (16 waves) per batch element; B=256 blocks = 256 CUs.
// LINEAR-domain recurrence (beta transform), math identical to r7-r9
// (absmax = 1 bf16 ulp) but with F64 STATE:
//     nO = (aO + pE + skip*pO) * w,  w = e^{x_lab - x_blank} clamped to
//          [6.1e-5, 8192];  nE = aE + aO;  state0 = r0;
//     w = 0 for lanes >= label_length (junk-state flush fix, r6).
// Round-9 lesson: waves issue IN ORDER -- a lagged renorm still stalls the
// pipeline for the reduction's serial latency (4 dependent DPP-max + readlane
// tree), and lag-4 doubled its frequency. Fix: cut renorm FREQUENCY with f64
// state: growth/step <= 3*2^13 < 2^14.6, so 32 steps grow <= 2^467 < 2^1023
// -> zero-lag renorm every 4 chunks, amortized ~C/32 cyc/step. The reduction
// uses u32 max on f64 high words (positive doubles order by high word).
// Readout extracts the f64 exponent via bit surgery (no f64 log).
// B=256, T=512, C=128 (blank=127), L=64, S=129.

constexpr int Cc = 128;
constexpr int Tt = 512;
constexpr int Ll = 64;
constexpr int NCk = Tt / 8;           // 64 chunks of 8 timesteps
constexpr float INV_LN2 = 1.4426950408889634f;
constexpr float LN2_F   = 0.6931471805599453f;

__device__ __forceinline__ float fexp2(float x) { return __builtin_amdgcn_exp2f(x); }
__device__ __forceinline__ float flog2(float x) { return __builtin_amdgcn_logf(x); }

template<int CTRL, bool BC>
__device__ __forceinline__ int dppi(int old, int x) {
    return __builtin_amdgcn_update_dpp(old, x, CTRL, 0xF, 0xF, BC);
}
template<int CTRL, bool BC>
__device__ __forceinline__ float dppf(float old, float x) {
    return __int_as_float(dppi<CTRL, BC>(__float_as_int(old), __float_as_int(x)));
}
// lane i <- lane i-1 across whole wave; lane 0 <- fill. (silicon-proven r3-r9)
__device__ __forceinline__ float wshr1(float x, float fill) { return dppf<0x138, false>(fill, x); }
// 64-bit variant: two independent 32-bit DPP moves on the halves.
__device__ __forceinline__ double wshr1_d(double x, double fill) {
    const int rl = dppi<0x138, false>(__double2loint(fill), __double2loint(x));
    const int rh = dppi<0x138, false>(__double2hiint(fill), __double2hiint(x));
    return __hiloint2double(rh, rl);
}

__device__ __forceinline__ float rlf(float v, int lane) {
    return __int_as_float(__builtin_amdgcn_readlane(__float_as_int(v), lane));
}
__device__ __forceinline__ unsigned rlu(unsigned v, int lane) {
    return (unsigned)__builtin_amdgcn_readlane((int)v, lane);
}
// Row-local (16-lane) reduce; lanes 15/31/47/63 hold row results. (proven r6-r9)
__device__ __forceinline__ float rowsum(float e) {
    e += dppf<0x111, true>(0.f, e);
    e += dppf<0x112, true>(0.f, e);
    e += dppf<0x114, true>(0.f, e);
    e += dppf<0x118, true>(0.f, e);
    return e;
}
__device__ __forceinline__ unsigned umaxu(unsigned a, unsigned b) { return a > b ? a : b; }
// u32 row-max (same row_shr pattern, 0-fill is identity for unsigned max)
__device__ __forceinline__ unsigned rowmax_u(unsigned m) {
    m = umaxu(m, (unsigned)dppi<0x111, true>(0, (int)m));
    m = umaxu(m, (unsigned)dppi<0x112, true>(0, (int)m));
    m = umaxu(m, (unsigned)dppi<0x114, true>(0, (int)m));
    m = umaxu(m, (unsigned)dppi<0x118, true>(0, (int)m));
    return m;
}
__device__ __forceinline__ unsigned allmax_u(unsigned m) {
    m = rowmax_u(m);
    return umaxu(umaxu(rlu(m, 15), rlu(m, 31)), umaxu(rlu(m, 47), rlu(m, 63)));
}
__device__ __forceinline__ float bperm_f(int srclane, float v) {
    return __int_as_float(__builtin_amdgcn_ds_bpermute(srclane << 2, __float_as_int(v)));
}
__device__ __forceinline__ float gather4(float4 v, int srclane, int csel) {
    const float gx = bperm_f(srclane, v.x), gy = bperm_f(srclane, v.y);
    const float gz = bperm_f(srclane, v.z), gw = bperm_f(srclane, v.w);
    const float lo = (csel & 1) ? gy : gx;
    const float hi = (csel & 1) ? gw : gz;
    return (csel & 2) ? hi : lo;
}

__global__ __launch_bounds__(1024, 1) void ctc_fused4_kernel(
    const int* __restrict__ y_true,      // [B, 64]
    const float* __restrict__ y_pred,    // [B, T, C]
    const int* __restrict__ in_len,      // [B]
    const int* __restrict__ lab_len,     // [B]
    float* __restrict__ out)             // [B]
{
    __shared__ __half w_lds[Tt / 8][64][8];   // [chunk][lane][t&7], 64 KB
    __shared__ float  ps[16];                 // per-wave blank partial sums (log2)

    const int b   = blockIdx.x;
    const int tid = threadIdx.x;
    const int w   = tid >> 6;            // wave 0..15
    const int l   = tid & 63;

    int inlen = in_len[b]; if (inlen < 1) inlen = 1; if (inlen > Tt) inlen = Tt;
    int LLv   = lab_len[b]; if (LLv < 1) LLv = 1; if (LLv > Ll) LLv = Ll;

    const int lab = y_true[b * Ll + l] & 127;
    const float* rowbase = y_pred + (size_t)b * Tt * Cc;

    // ---------------- prep: wave w handles rows [w*32, w*32+32) ---------------- (proven r8/r9)
    const int half = l >> 5, li = l & 31;
    const int srcA = lab >> 2;           // lane (in low half) holding class `lab`
    const int csel = lab & 3;
    const int tbase = w * 32;
    const bool live = (l < LLv);         // r6 fix: dead lattice lanes -> w = 0

    float4 vb[4];
#pragma unroll
    for (int j = 0; j < 4; ++j)
        vb[j] = ((const float4*)(rowbase + (size_t)(tbase + 2 * j + half) * Cc))[li];

    float acc = 0.0f;                    // sum of lp2_blank over this wave's rows (< inlen)

    for (int i = 0; i < 16; i += 4) {
#pragma unroll
        for (int j = 0; j < 4; ++j) {
            const float4 v = vb[j];
            const int nx = i + 4 + j;
            if (nx < 16)
                vb[j] = ((const float4*)(rowbase + (size_t)(tbase + 2 * nx + half) * Cc))[li];

            const int rA = tbase + 2 * (i + j);
            const int rB = rA + 1;

            // lse (log2) for both rows: row_shr partial sums + readlane combine
            float e = (fexp2(v.x * INV_LN2) + fexp2(v.y * INV_LN2))
                    + (fexp2(v.z * INV_LN2) + fexp2(v.w * INV_LN2));
            e = rowsum(e);
            const float sA = rlf(e, 15) + rlf(e, 31);
            const float sB = rlf(e, 47) + rlf(e, 63);
            const float lsA = flog2(sA), lsB = flog2(sB);
            const float blA = rlf(v.w, 31);      // blank logit, row A (uniform)
            const float blB = rlf(v.w, 63);      // blank logit, row B

            const float lpbA = fmaf(blA, INV_LN2, -lsA);
            const float lpbB = fmaf(blB, INV_LN2, -lsB);
            acc += ((rA < inlen) ? lpbA : 0.0f) + ((rB < inlen) ? lpbB : 0.0f);

            // per-lane label weights -> LDS chunk layout
            const float xA = gather4(v, srcA, csel);
            const float xB = gather4(v, srcA + 32, csel);
            float wA = fminf(fmaxf(fexp2((xA - blA) * INV_LN2), 6.1e-5f), 8192.0f);
            float wB = fminf(fmaxf(fexp2((xB - blB) * INV_LN2), 6.1e-5f), 8192.0f);
            wA = live ? wA : 0.0f;
            wB = live ? wB : 0.0f;
            const unsigned packed =
                  (unsigned)__half_as_ushort(__float2half(wA))
                | ((unsigned)__half_as_ushort(__float2half(wB)) << 16);
            *(unsigned*)&w_lds[rA >> 3][l][rA & 7] = packed;   // rA even: 4B aligned
        }
    }
    if (l == 0) ps[w] = acc;

    __syncthreads();
    if (w != 0) return;

    // ---------------- chain: wave 0, 512-step f64 linear recurrence ----------------
    const int labp = __shfl_up(lab, 1, 64);
    const bool skb = (l >= 1) && (lab != labp);

    double aO = 0.0, aE = 0.0, r0 = 1.0;
    float Rtot = 0.0f;

    const int nchunks = (inlen + 7) >> 3;       // >= 32 for this data
    uint4 A = *(const uint4*)&w_lds[0][l][0];
    for (int c = 0; c < nchunks; ++c) {
        const int nx = (c + 1 < NCk) ? c + 1 : NCk - 1;
        const uint4 Bv = *(const uint4*)&w_lds[nx][l][0];   // prefetch next chunk

        double wd[8];
        {
            const __half2 h0 = *reinterpret_cast<const __half2*>(&A.x);
            const __half2 h1 = *reinterpret_cast<const __half2*>(&A.y);
            const __half2 h2 = *reinterpret_cast<const __half2*>(&A.z);
            const __half2 h3 = *reinterpret_cast<const __half2*>(&A.w);
            wd[0] = (double)__low2float(h0); wd[1] = (double)__high2float(h0);
            wd[2] = (double)__low2float(h1); wd[3] = (double)__high2float(h1);
            wd[4] = (double)__low2float(h2); wd[5] = (double)__high2float(h2);
            wd[6] = (double)__low2float(h3); wd[7] = (double)__high2float(h3);
        }

        const int t0 = c * 8;
        if (t0 + 8 <= inlen) {
#pragma unroll
            for (int j = 0; j < 8; ++j) {
                const double pE = wshr1_d(aE, r0);     // beta[2l]; lane0: state0
                const double pO = wshr1_d(aO, 0.0);    // beta[2l-1]
                const double pOs = skb ? pO : 0.0;     // 2x cndmask, no mul
                const double nO = (aO + pE + pOs) * wd[j];
                aE += aO;
                aO = nO;
            }
        } else {
#pragma unroll
            for (int j = 0; j < 8; ++j) {
                if (t0 + j < inlen) {
                    const double pE = wshr1_d(aE, r0);
                    const double pO = wshr1_d(aO, 0.0);
                    const double pOs = skb ? pO : 0.0;
                    const double nO = (aO + pE + pOs) * wd[j];
                    aE += aO;
                    aO = nO;
                }
            }
        }
        A = Bv;

        // zero-lag renorm every 4 chunks (32 steps): growth <= 2^467 < 2^1023.
        // u32 max of f64 high words (positive doubles order by high word).
        if ((c & 3) == 3) {
            unsigned m = umaxu(umaxu((unsigned)__double2hiint(aE),
                                     (unsigned)__double2hiint(aO)),
                               (unsigned)__double2hiint(r0));
            const unsigned M = allmax_u(m);
            int R = (int)(M >> 20) - 1023;             // exponent of wave max
            R = (R < -1020) ? -1020 : ((R > 1020) ? 1020 : R);
            const double sc = __hiloint2double((1023 - R) << 20, 0);  // exact 2^-R
            aO *= sc; aE *= sc; r0 *= sc;
            Rtot += (float)R;
        }
    }

    // cum_blank (log2): sum the 16 per-wave partials (uniform)
    float cum_b = 0.0f;
#pragma unroll
    for (int q = 0; q < 16; ++q) cum_b += ps[q];

    // readout: states 2*LL (aE) and 2*LL-1 (aO) live on lane LL-1.
    // log2 via f64 exponent surgery (states can be up to ~2^467).
    const double aEr = __shfl(aE, LLv - 1, 64);
    const double aOr = __shfl(aO, LLv - 1, 64);
    if (l == 0) {
        double v = aEr + aOr;
        if (!(v > 0.0)) v = 1e-300;                    // guard (never hit on valid rows)
        const int hi = __double2hiint(v);
        const int e2 = ((hi >> 20) & 0x7ff) - 1023;
        const double mant = __hiloint2double((hi & 0x000FFFFF) | (1023 << 20),
                                             __double2loint(v));   // in [1,2)
        const float lg = flog2((float)mant) + (float)e2;
        out[b] = -LN2_F * (lg + Rtot + cum_b);
    }
}

extern "C" void kernel_launch(void* const* d_in, const int* in_sizes, int n_in,
                              void* d_out, int out_size, void* d_ws, size_t ws_size,
                              hipStream_t stream) {
    const int*   y_true  = (const int*)d_in[0];    // [256,64]
    const float* y_pred  = (const float*)d_in[1];  // [256,512,128]
    const int*   in_len  = (const int*)d_in[2];    // [256]
    const int*   lab_len = (const int*)d_in[3];    // [256]
    float*       out     = (float*)d_out;          // [256]
    (void)d_ws; (void)ws_size;

    ctc_fused4_kernel<<<256, 1024, 0, stream>>>(y_true, y_pred, in_len, lab_len, out);
}